// Round 4
// baseline (957.051 us; speedup 1.0000x reference)
//
#include <hip/hip_runtime.h>
#include <stdint.h>
#include <stddef.h>

#define TOKS 4096
#define DH   2048
#define DI   8192

typedef __attribute__((ext_vector_type(8))) short short8v;
typedef __attribute__((ext_vector_type(4))) short short4v;
typedef __attribute__((ext_vector_type(4))) float floatx4;

__device__ __forceinline__ float b2f(short s) {
  union { unsigned u; float f; } v;
  v.u = ((unsigned)(unsigned short)s) << 16;
  return v.f;
}
__device__ __forceinline__ short f2b(float f) {
  union { float f; unsigned u; } v; v.f = f;
  unsigned r = (v.u + 0x7fffu + ((v.u >> 16) & 1u)) >> 16;  // RNE
  return (short)(unsigned short)r;
}
__device__ __forceinline__ void gload_lds16(const void* g, void* l) {
  __builtin_amdgcn_global_load_lds((const __attribute__((address_space(1))) void*)g,
                                   (__attribute__((address_space(3))) void*)l, 16, 0, 0);
}

// ---------------- fp32 -> bf16 elementwise (x) ----------------
__global__ __launch_bounds__(256) void cvt_f32_to_bf16(const float* __restrict__ in,
                                                       short* __restrict__ out) {
  size_t i = (size_t)blockIdx.x * 256 + threadIdx.x;
  floatx4 v = *(const floatx4*)&in[i * 4];
  short4v o;
  o[0] = f2b(v[0]); o[1] = f2b(v[1]); o[2] = f2b(v[2]); o[3] = f2b(v[3]);
  *(short4v*)&out[i * 4] = o;
}

// ---- fp32 [K][N] -> bf16 [N][K] transpose; z selects {wg->even, wu->odd} ----
__global__ __launch_bounds__(256) void transpose_gu(const float* __restrict__ in0,
                                                    const float* __restrict__ in1,
                                                    short* __restrict__ out) {
  const float* in = blockIdx.z ? in1 : in0;
  const int roff = blockIdx.z;
  __shared__ float tile[32][33];
  const int n0 = blockIdx.x * 32, k0 = blockIdx.y * 32;
  const int tx = threadIdx.x & 31, ty = threadIdx.x >> 5;
#pragma unroll
  for (int yy = 0; yy < 32; yy += 8)
    tile[ty + yy][tx] = in[(size_t)(k0 + ty + yy) * DI + n0 + tx];
  __syncthreads();
#pragma unroll
  for (int yy = 0; yy < 32; yy += 8)
    out[((size_t)(n0 + ty + yy) * 2 + roff) * DH + k0 + tx] = f2b(tile[tx][ty + yy]);
}

__global__ __launch_bounds__(256) void transpose_to_bf16(const float* __restrict__ in,
                                                         short* __restrict__ out,
                                                         int K, int N) {
  __shared__ float tile[32][33];
  const int n0 = blockIdx.x * 32, k0 = blockIdx.y * 32;
  const int tx = threadIdx.x & 31, ty = threadIdx.x >> 5;
#pragma unroll
  for (int yy = 0; yy < 32; yy += 8)
    tile[ty + yy][tx] = in[(size_t)(k0 + ty + yy) * N + n0 + tx];
  __syncthreads();
#pragma unroll
  for (int yy = 0; yy < 32; yy += 8)
    out[(size_t)(n0 + ty + yy) * K + k0 + tx] = f2b(tile[tx][ty + yy]);
}

// ---------------- router + const-expert gates (fp32 exact) ----------------
#define RT_TPB 8
__global__ __launch_bounds__(256) void router_kernel(const float* __restrict__ x,
                                                     const float* __restrict__ gw1,
                                                     const float* __restrict__ gw2,
                                                     const float* __restrict__ cwg,
                                                     float* __restrict__ logits_out,
                                                     float* __restrict__ coef) {
  const int wave = threadIdx.x >> 6, lane = threadIdx.x & 63;
  const int tok0 = blockIdx.x * RT_TPB;
  __shared__ float xs[RT_TPB][512];
  __shared__ float ll[RT_TPB][8];
  __shared__ float cd[RT_TPB][4];

  float tj[2] = {0.f, 0.f};
  float cda[2][4] = {{0.f,0.f,0.f,0.f},{0.f,0.f,0.f,0.f}};

  const int st = threadIdx.x >> 5;
  const int sl = threadIdx.x & 31;

  for (int c = 0; c < 4; ++c) {
    const int dbase = c * 512;
#pragma unroll
    for (int r = 0; r < 4; ++r) {
      const int idx = r * 128 + sl * 4;
      *(floatx4*)&xs[st][idx] = *(const floatx4*)&x[(size_t)(tok0 + st) * DH + dbase + idx];
    }
    __syncthreads();
    for (int d = 0; d < 512; ++d) {
      const float g = gw1[(size_t)(dbase + d) * 64 + lane];
      tj[0] += xs[wave * 2 + 0][d] * g;
      tj[1] += xs[wave * 2 + 1][d] * g;
    }
#pragma unroll
    for (int dq = 0; dq < 8; ++dq) {
      const int d = dq * 64 + lane;
      const float w0 = cwg[(size_t)(dbase + d) * 2 + 0];
      const float w1 = cwg[(size_t)(dbase + d) * 2 + 1];
      const float w2 = cwg[(size_t)DH * 2 + (dbase + d) * 2 + 0];
      const float w3 = cwg[(size_t)DH * 2 + (dbase + d) * 2 + 1];
#pragma unroll
      for (int t = 0; t < 2; ++t) {
        const float xv = xs[wave * 2 + t][d];
        cda[t][0] += xv * w0; cda[t][1] += xv * w1;
        cda[t][2] += xv * w2; cda[t][3] += xv * w3;
      }
    }
    __syncthreads();
  }

#pragma unroll
  for (int t = 0; t < 2; ++t) {
    const float th = tanhf(tj[t]);
#pragma unroll
    for (int e = 0; e < 8; ++e) {
      float p = th * gw2[lane * 8 + e];
      for (int off = 32; off; off >>= 1) p += __shfl_xor(p, off);
      if (lane == 0) ll[wave * 2 + t][e] = p;
    }
#pragma unroll
    for (int dd = 0; dd < 4; ++dd) {
      float p = cda[t][dd];
      for (int off = 32; off; off >>= 1) p += __shfl_xor(p, off);
      if (lane == 0) cd[wave * 2 + t][dd] = p;
    }
  }
  __syncthreads();

  if (threadIdx.x < RT_TPB) {
    const int t = threadIdx.x;
    const int gtok = tok0 + t;
    float l[8];
#pragma unroll
    for (int e = 0; e < 8; ++e) l[e] = ll[t][e];
#pragma unroll
    for (int e = 0; e < 8; ++e) logits_out[(size_t)gtok * 8 + e] = l[e];
    float m = l[0];
#pragma unroll
    for (int e = 1; e < 8; ++e) m = fmaxf(m, l[e]);
    float p[8], s = 0.f;
#pragma unroll
    for (int e = 0; e < 8; ++e) { p[e] = expf(l[e] - m); s += p[e]; }
#pragma unroll
    for (int e = 0; e < 8; ++e) p[e] /= s;
    int i1 = 0;
#pragma unroll
    for (int e = 1; e < 8; ++e) if (p[e] > p[i1]) i1 = e;
    int i2 = -1;
#pragma unroll
    for (int e = 0; e < 8; ++e) {
      if (e == i1) continue;
      if (i2 < 0 || p[e] > p[i2]) i2 = e;
    }
    float w1 = (i1 == 7) ? 0.f : p[i1];
    float w2 = (i2 == 7) ? 0.f : p[i2];
    const float nrm = w1 + w2;
    w1 /= nrm; w2 /= nrm;
    float pe[8];
#pragma unroll
    for (int e = 0; e < 8; ++e) pe[e] = 0.f;
    pe[i1] += w1; pe[i2] += w2;
    const float cw00 = 1.f / (1.f + expf(cd[t][1] - cd[t][0]));
    const float cw10 = 1.f / (1.f + expf(cd[t][3] - cd[t][2]));
    coef[gtok * 4 + 0] = pe[0] + pe[2] * cw00 + pe[3] * cw10;
    coef[gtok * 4 + 1] = pe[2] * (1.f - cw00);
    coef[gtok * 4 + 2] = pe[3] * (1.f - cw10);
    coef[gtok * 4 + 3] = pe[4] + pe[5] + pe[6] + pe[7];
  }
}

// ---------------- bf16 MFMA GEMM mainloop: BK=64, XOR-swizzled LDS ----------
__device__ __forceinline__ void gemm_mainloop(const short* __restrict__ A,
                                              const short* __restrict__ Bt,
                                              int K, int lda, int ldb,
                                              int m0, int n0,
                                              short* As, short* Bs,
                                              floatx4 (&acc)[4][4]) {
  const int wave = threadIdx.x >> 6;
  const int lane = threadIdx.x & 63;
  const int srow = lane >> 3;
  const int scol = ((lane & 7) ^ srow) * 8;
  const int wm = (wave & 1) * 64;
  const int wn = (wave >> 1) * 64;
  const int l15 = lane & 15;
  const int quad = lane >> 4;
  const int q0 = ((quad ^ (l15 & 7)) * 8);

  for (int k0 = 0; k0 < K; k0 += 64) {
#pragma unroll
    for (int q = 0; q < 4; ++q) {
      const int chunk = wave * 4 + q;
      const int row = chunk * 8 + srow;
      gload_lds16(A + (size_t)(m0 + row) * lda + k0 + scol, &As[chunk * 8 * 64]);
      gload_lds16(Bt + (size_t)(n0 + row) * ldb + k0 + scol, &Bs[chunk * 8 * 64]);
    }
    __syncthreads();
#pragma unroll
    for (int kk = 0; kk < 2; ++kk) {
      const int qo = q0 ^ (kk * 32);
      short8v af[4], bf[4];
#pragma unroll
      for (int i = 0; i < 4; ++i) {
        af[i] = *(const short8v*)&As[(wm + i * 16 + l15) * 64 + qo];
        bf[i] = *(const short8v*)&Bs[(wn + i * 16 + l15) * 64 + qo];
      }
#pragma unroll
      for (int mi = 0; mi < 4; ++mi)
#pragma unroll
        for (int ni = 0; ni < 4; ++ni)
          acc[mi][ni] = __builtin_amdgcn_mfma_f32_16x16x32_bf16(af[mi], bf[ni],
                                                                acc[mi][ni], 0, 0, 0);
    }
    __syncthreads();
  }
}

// GEMM1 fused: Bt interleaved [2n]=g_col n, [2n+1]=u_col n. Writes H=silu(g)*u.
__global__ __launch_bounds__(256) void gemm1_gu_silu(const short* __restrict__ A,
                                                     const short* __restrict__ Bt,
                                                     short* __restrict__ H) {
  __shared__ short As[128 * 64];
  __shared__ short Bs[128 * 64];
  floatx4 acc[4][4];
#pragma unroll
  for (int a = 0; a < 4; ++a)
#pragma unroll
    for (int b = 0; b < 4; ++b) acc[a][b] = (floatx4)0.0f;
  const int lin = blockIdx.y * gridDim.x + blockIdx.x;
  const int m0 = (lin & 31) * 128, n0 = (lin >> 5) * 128;
  gemm_mainloop(A, Bt, DH, DH, DH, m0, n0, As, Bs, acc);
  const int wave = threadIdx.x >> 6, lane = threadIdx.x & 63;
  const int wm = (wave & 1) * 64, wn = (wave >> 1) * 64;
  const int l15 = lane & 15, q4 = (lane >> 4) * 4;
#pragma unroll
  for (int mi = 0; mi < 4; ++mi) {
    const int row0 = m0 + wm + mi * 16 + q4;
#pragma unroll
    for (int ni = 0; ni < 4; ++ni) {
      const int col = n0 + wn + ni * 16 + l15;
#pragma unroll
      for (int rg = 0; rg < 4; ++rg) {
        const float v = acc[mi][ni][rg];
        const float p = __shfl_xor(v, 1);
        if ((l15 & 1) == 0) {
          const float h = (v / (1.f + __expf(-v))) * p;
          H[(size_t)(row0 + rg) * DI + (col >> 1)] = f2b(h);
        }
      }
    }
  }
}

// GEMM2 split-K: z = K-chunk (0/1), each block does K=4096, stores fp32 partials.
__global__ __launch_bounds__(256) void gemm2_splitk(const short* __restrict__ A,
                                                    const short* __restrict__ Bt,
                                                    float* __restrict__ P) {
  __shared__ short As[128 * 64];
  __shared__ short Bs[128 * 64];
  floatx4 acc[4][4];
#pragma unroll
  for (int a = 0; a < 4; ++a)
#pragma unroll
    for (int b = 0; b < 4; ++b) acc[a][b] = (floatx4)0.0f;
  const int lin = blockIdx.y * gridDim.x + blockIdx.x;
  const int m0 = (lin & 31) * 128, n0 = (lin >> 5) * 128;
  const int kofs = blockIdx.z * (DI / 2);
  gemm_mainloop(A + kofs, Bt + kofs, DI / 2, DI, DI, m0, n0, As, Bs, acc);
  float* Pz = P + (size_t)blockIdx.z * TOKS * DH;
  const int wave = threadIdx.x >> 6, lane = threadIdx.x & 63;
  const int wm = (wave & 1) * 64, wn = (wave >> 1) * 64;
  const int l15 = lane & 15, q4 = (lane >> 4) * 4;
#pragma unroll
  for (int mi = 0; mi < 4; ++mi) {
    const int row0 = m0 + wm + mi * 16 + q4;
#pragma unroll
    for (int ni = 0; ni < 4; ++ni) {
      const int col = n0 + wn + ni * 16 + l15;
#pragma unroll
      for (int rg = 0; rg < 4; ++rg)
        Pz[(size_t)(row0 + rg) * DH + col] = acc[mi][ni][rg];
    }
  }
}

// Combine: out = cf.x*x + cf.y*c0 + cf.z*c1 + cf.w*(p0+p1)
__global__ __launch_bounds__(256) void moe_combine(const float* __restrict__ P,
                                                   const float* __restrict__ x,
                                                   const float* __restrict__ cc,
                                                   const float* __restrict__ coef,
                                                   float* __restrict__ out) {
  const size_t i = ((size_t)blockIdx.x * 256 + threadIdx.x) * 4;
  const int row = (int)(i >> 11);
  const int col = (int)(i & 2047);
  const floatx4 p0 = *(const floatx4*)&P[i];
  const floatx4 p1 = *(const floatx4*)&P[(size_t)TOKS * DH + i];
  const floatx4 xv = *(const floatx4*)&x[i];
  const floatx4 c0 = *(const floatx4*)&cc[col];
  const floatx4 c1 = *(const floatx4*)&cc[DH + col];
  const floatx4 cf = *(const floatx4*)&coef[row * 4];
  floatx4 o;
#pragma unroll
  for (int e = 0; e < 4; ++e)
    o[e] = cf[0] * xv[e] + cf[1] * c0[e] + cf[2] * c1[e] + cf[3] * (p0[e] + p1[e]);
  *(floatx4*)&out[i] = o;
}

extern "C" void kernel_launch(void* const* d_in, const int* in_sizes, int n_in,
                              void* d_out, int out_size, void* d_ws, size_t ws_size,
                              hipStream_t stream) {
  const float* x   = (const float*)d_in[0];
  const float* gw1 = (const float*)d_in[1];
  const float* gw2 = (const float*)d_in[2];
  const float* cwg = (const float*)d_in[3];
  const float* cc  = (const float*)d_in[4];
  const float* wg  = (const float*)d_in[5];
  const float* wu  = (const float*)d_in[6];
  const float* wd  = (const float*)d_in[7];
  float* out = (float*)d_out;
  float* logits_out = out + (size_t)TOKS * DH;

  char* ws = (char*)d_ws;
  short* xb    = (short*)(ws);                          // 16.78 MB
  short* wgwuT = (short*)(ws + 16777216);               // [16384][2048] bf16 interleaved
  short* wdT   = (short*)(ws + 16777216 + 67108864);    // [2048][8192] bf16
  short* H     = (short*)(ws + 117440512);              // [4096][8192] bf16
  float* P     = (float*)(ws + 117440512 + 67108864);   // [2][4096][2048] fp32, 67.1 MB
  float* coef  = (float*)(ws + 117440512 + 67108864 + 67108864);  // [4096][4] fp32

  cvt_f32_to_bf16<<<(TOKS * DH) / (256 * 4), 256, 0, stream>>>(x, xb);
  transpose_gu<<<dim3(DI / 32, DH / 32, 2), 256, 0, stream>>>(wg, wu, wgwuT);
  transpose_to_bf16<<<dim3(DH / 32, DI / 32), 256, 0, stream>>>(wd, wdT, DI, DH);
  router_kernel<<<TOKS / RT_TPB, 256, 0, stream>>>(x, gw1, gw2, cwg, logits_out, coef);
  gemm1_gu_silu<<<dim3((2 * DI) / 128, TOKS / 128), 256, 0, stream>>>(xb, wgwuT, H);
  gemm2_splitk<<<dim3(DH / 128, TOKS / 128, 2), 256, 0, stream>>>(H, wdT, P);
  moe_combine<<<(TOKS * DH) / (256 * 4), 256, 0, stream>>>(P, x, cc, coef, out);
}

// Round 5
// 904.376 us; speedup vs baseline: 1.0582x; 1.0582x over previous
//
#include <hip/hip_runtime.h>
#include <stdint.h>
#include <stddef.h>

#define TOKS 4096
#define DH   2048
#define DI   8192

typedef __attribute__((ext_vector_type(8))) short short8v;
typedef __attribute__((ext_vector_type(4))) short short4v;
typedef __attribute__((ext_vector_type(4))) float floatx4;

__device__ __forceinline__ float b2f(short s) {
  union { unsigned u; float f; } v;
  v.u = ((unsigned)(unsigned short)s) << 16;
  return v.f;
}
__device__ __forceinline__ short f2b(float f) {
  union { float f; unsigned u; } v; v.f = f;
  unsigned r = (v.u + 0x7fffu + ((v.u >> 16) & 1u)) >> 16;  // RNE
  return (short)(unsigned short)r;
}
__device__ __forceinline__ void gload_lds16(const void* g, void* l) {
  __builtin_amdgcn_global_load_lds((const __attribute__((address_space(1))) void*)g,
                                   (__attribute__((address_space(3))) void*)l, 16, 0, 0);
}

// ---------------- fp32 -> bf16 elementwise (x) ----------------
__global__ __launch_bounds__(256) void cvt_f32_to_bf16(const float* __restrict__ in,
                                                       short* __restrict__ out) {
  size_t i = (size_t)blockIdx.x * 256 + threadIdx.x;
  floatx4 v = *(const floatx4*)&in[i * 4];
  short4v o;
  o[0] = f2b(v[0]); o[1] = f2b(v[1]); o[2] = f2b(v[2]); o[3] = f2b(v[3]);
  *(short4v*)&out[i * 4] = o;
}

// ---- fp32 [K][N] -> bf16 [N*rstride+roff][K] transpose, vectorized ----
// 64x64 tile; float4 global loads, short8 global stores.
__global__ __launch_bounds__(256) void transpose_v2(const float* __restrict__ in,
                                                    short* __restrict__ out,
                                                    int K, int N,
                                                    int rstride, int roff) {
  __shared__ float tile[64][68];   // stride 68 words: 16B-aligned rows
  const int n0 = blockIdx.x * 64, k0 = blockIdx.y * 64;
  const int t = threadIdx.x;
  {
    const int r = t >> 4;          // 0..15
    const int c = (t & 15) * 4;    // 0..60
#pragma unroll
    for (int p = 0; p < 4; ++p) {
      const floatx4 v = *(const floatx4*)&in[(size_t)(k0 + p * 16 + r) * N + n0 + c];
      *(floatx4*)&tile[p * 16 + r][c] = v;
    }
  }
  __syncthreads();
  {
    const int n = t >> 3;          // 0..31
    const int kc = (t & 7) * 8;    // 0..56
#pragma unroll
    for (int p = 0; p < 2; ++p) {
      const int nn = p * 32 + n;
      short8v o;
#pragma unroll
      for (int j = 0; j < 8; ++j) o[j] = f2b(tile[kc + j][nn]);
      *(short8v*)&out[((size_t)(n0 + nn) * rstride + roff) * K + k0 + kc] = o;
    }
  }
}

// ---------------- router + const-expert gates (fp32 exact) ----------------
#define RT_TPB 8
__global__ __launch_bounds__(256) void router_kernel(const float* __restrict__ x,
                                                     const float* __restrict__ gw1,
                                                     const float* __restrict__ gw2,
                                                     const float* __restrict__ cwg,
                                                     float* __restrict__ logits_out,
                                                     float* __restrict__ coef) {
  const int wave = threadIdx.x >> 6, lane = threadIdx.x & 63;
  const int tok0 = blockIdx.x * RT_TPB;
  __shared__ float xs[RT_TPB][512];
  __shared__ float ll[RT_TPB][8];
  __shared__ float cd[RT_TPB][4];

  float tj[2] = {0.f, 0.f};
  float cda[2][4] = {{0.f,0.f,0.f,0.f},{0.f,0.f,0.f,0.f}};

  const int st = threadIdx.x >> 5;
  const int sl = threadIdx.x & 31;

  for (int c = 0; c < 4; ++c) {
    const int dbase = c * 512;
#pragma unroll
    for (int r = 0; r < 4; ++r) {
      const int idx = r * 128 + sl * 4;
      *(floatx4*)&xs[st][idx] = *(const floatx4*)&x[(size_t)(tok0 + st) * DH + dbase + idx];
    }
    __syncthreads();
    for (int d = 0; d < 512; ++d) {
      const float g = gw1[(size_t)(dbase + d) * 64 + lane];
      tj[0] += xs[wave * 2 + 0][d] * g;
      tj[1] += xs[wave * 2 + 1][d] * g;
    }
#pragma unroll
    for (int dq = 0; dq < 8; ++dq) {
      const int d = dq * 64 + lane;
      const float w0 = cwg[(size_t)(dbase + d) * 2 + 0];
      const float w1 = cwg[(size_t)(dbase + d) * 2 + 1];
      const float w2 = cwg[(size_t)DH * 2 + (dbase + d) * 2 + 0];
      const float w3 = cwg[(size_t)DH * 2 + (dbase + d) * 2 + 1];
#pragma unroll
      for (int t = 0; t < 2; ++t) {
        const float xv = xs[wave * 2 + t][d];
        cda[t][0] += xv * w0; cda[t][1] += xv * w1;
        cda[t][2] += xv * w2; cda[t][3] += xv * w3;
      }
    }
    __syncthreads();
  }

#pragma unroll
  for (int t = 0; t < 2; ++t) {
    const float th = tanhf(tj[t]);
#pragma unroll
    for (int e = 0; e < 8; ++e) {
      float p = th * gw2[lane * 8 + e];
      for (int off = 32; off; off >>= 1) p += __shfl_xor(p, off);
      if (lane == 0) ll[wave * 2 + t][e] = p;
    }
#pragma unroll
    for (int dd = 0; dd < 4; ++dd) {
      float p = cda[t][dd];
      for (int off = 32; off; off >>= 1) p += __shfl_xor(p, off);
      if (lane == 0) cd[wave * 2 + t][dd] = p;
    }
  }
  __syncthreads();

  if (threadIdx.x < RT_TPB) {
    const int t = threadIdx.x;
    const int gtok = tok0 + t;
    float l[8];
#pragma unroll
    for (int e = 0; e < 8; ++e) l[e] = ll[t][e];
#pragma unroll
    for (int e = 0; e < 8; ++e) logits_out[(size_t)gtok * 8 + e] = l[e];
    float m = l[0];
#pragma unroll
    for (int e = 1; e < 8; ++e) m = fmaxf(m, l[e]);
    float p[8], s = 0.f;
#pragma unroll
    for (int e = 0; e < 8; ++e) { p[e] = expf(l[e] - m); s += p[e]; }
#pragma unroll
    for (int e = 0; e < 8; ++e) p[e] /= s;
    int i1 = 0;
#pragma unroll
    for (int e = 1; e < 8; ++e) if (p[e] > p[i1]) i1 = e;
    int i2 = -1;
#pragma unroll
    for (int e = 0; e < 8; ++e) {
      if (e == i1) continue;
      if (i2 < 0 || p[e] > p[i2]) i2 = e;
    }
    float w1 = (i1 == 7) ? 0.f : p[i1];
    float w2 = (i2 == 7) ? 0.f : p[i2];
    const float nrm = w1 + w2;
    w1 /= nrm; w2 /= nrm;
    float pe[8];
#pragma unroll
    for (int e = 0; e < 8; ++e) pe[e] = 0.f;
    pe[i1] += w1; pe[i2] += w2;
    const float cw00 = 1.f / (1.f + expf(cd[t][1] - cd[t][0]));
    const float cw10 = 1.f / (1.f + expf(cd[t][3] - cd[t][2]));
    coef[gtok * 4 + 0] = pe[0] + pe[2] * cw00 + pe[3] * cw10;
    coef[gtok * 4 + 1] = pe[2] * (1.f - cw00);
    coef[gtok * 4 + 2] = pe[3] * (1.f - cw10);
    coef[gtok * 4 + 3] = pe[4] + pe[5] + pe[6] + pe[7];
  }
}

// ---------------- bf16 MFMA GEMM mainloop: BK=64, XOR-swizzled LDS ----------
// K/lda/ldb MUST stay runtime args: const-folding them regressed 25% (r4).
__device__ __forceinline__ void gemm_mainloop(const short* __restrict__ A,
                                              const short* __restrict__ Bt,
                                              int K, int lda, int ldb,
                                              int m0, int n0,
                                              short* As, short* Bs,
                                              floatx4 (&acc)[4][4]) {
  const int wave = threadIdx.x >> 6;
  const int lane = threadIdx.x & 63;
  const int srow = lane >> 3;
  const int scol = ((lane & 7) ^ srow) * 8;
  const int wm = (wave & 1) * 64;
  const int wn = (wave >> 1) * 64;
  const int l15 = lane & 15;
  const int quad = lane >> 4;
  const int q0 = ((quad ^ (l15 & 7)) * 8);

  for (int k0 = 0; k0 < K; k0 += 64) {
#pragma unroll
    for (int q = 0; q < 4; ++q) {
      const int chunk = wave * 4 + q;
      const int row = chunk * 8 + srow;
      gload_lds16(A + (size_t)(m0 + row) * lda + k0 + scol, &As[chunk * 8 * 64]);
      gload_lds16(Bt + (size_t)(n0 + row) * ldb + k0 + scol, &Bs[chunk * 8 * 64]);
    }
    __syncthreads();
#pragma unroll
    for (int kk = 0; kk < 2; ++kk) {
      const int qo = q0 ^ (kk * 32);
      short8v af[4], bf[4];
#pragma unroll
      for (int i = 0; i < 4; ++i) {
        af[i] = *(const short8v*)&As[(wm + i * 16 + l15) * 64 + qo];
        bf[i] = *(const short8v*)&Bs[(wn + i * 16 + l15) * 64 + qo];
      }
#pragma unroll
      for (int mi = 0; mi < 4; ++mi)
#pragma unroll
        for (int ni = 0; ni < 4; ++ni)
          acc[mi][ni] = __builtin_amdgcn_mfma_f32_16x16x32_bf16(af[mi], bf[ni],
                                                                acc[mi][ni], 0, 0, 0);
    }
    __syncthreads();
  }
}

// GEMM1 fused: Bt interleaved [2n]=g_col n, [2n+1]=u_col n. Writes H=silu(g)*u.
__global__ __launch_bounds__(256) void gemm1_gu_silu(const short* __restrict__ A,
                                                     const short* __restrict__ Bt,
                                                     short* __restrict__ H,
                                                     int K, int lda, int ldb) {
  __shared__ short As[128 * 64];
  __shared__ short Bs[128 * 64];
  floatx4 acc[4][4];
#pragma unroll
  for (int a = 0; a < 4; ++a)
#pragma unroll
    for (int b = 0; b < 4; ++b) acc[a][b] = (floatx4)0.0f;
  const int lin = blockIdx.y * gridDim.x + blockIdx.x;
  const int m0 = (lin & 31) * 128, n0 = (lin >> 5) * 128;
  gemm_mainloop(A, Bt, K, lda, ldb, m0, n0, As, Bs, acc);
  const int wave = threadIdx.x >> 6, lane = threadIdx.x & 63;
  const int wm = (wave & 1) * 64, wn = (wave >> 1) * 64;
  const int l15 = lane & 15, q4 = (lane >> 4) * 4;
#pragma unroll
  for (int mi = 0; mi < 4; ++mi) {
    const int row0 = m0 + wm + mi * 16 + q4;
#pragma unroll
    for (int ni = 0; ni < 4; ++ni) {
      const int col = n0 + wn + ni * 16 + l15;
#pragma unroll
      for (int rg = 0; rg < 4; ++rg) {
        const float v = acc[mi][ni][rg];
        const float p = __shfl_xor(v, 1);
        if ((l15 & 1) == 0) {
          const float h = (v / (1.f + __expf(-v))) * p;
          H[(size_t)(row0 + rg) * DI + (col >> 1)] = f2b(h);
        }
      }
    }
  }
}

// GEMM2 split-K: z-th block does K=Ksub starting at z*Ksub, stores fp32 partials.
__global__ __launch_bounds__(256) void gemm2_splitk(const short* __restrict__ A,
                                                    const short* __restrict__ Bt,
                                                    float* __restrict__ P,
                                                    int Ksub, int lda, int ldb) {
  __shared__ short As[128 * 64];
  __shared__ short Bs[128 * 64];
  floatx4 acc[4][4];
#pragma unroll
  for (int a = 0; a < 4; ++a)
#pragma unroll
    for (int b = 0; b < 4; ++b) acc[a][b] = (floatx4)0.0f;
  const int lin = blockIdx.y * gridDim.x + blockIdx.x;
  const int m0 = (lin & 31) * 128, n0 = (lin >> 5) * 128;
  const int kofs = blockIdx.z * Ksub;
  gemm_mainloop(A + kofs, Bt + kofs, Ksub, lda, ldb, m0, n0, As, Bs, acc);
  float* Pz = P + (size_t)blockIdx.z * TOKS * DH;
  const int wave = threadIdx.x >> 6, lane = threadIdx.x & 63;
  const int wm = (wave & 1) * 64, wn = (wave >> 1) * 64;
  const int l15 = lane & 15, q4 = (lane >> 4) * 4;
#pragma unroll
  for (int mi = 0; mi < 4; ++mi) {
    const int row0 = m0 + wm + mi * 16 + q4;
#pragma unroll
    for (int ni = 0; ni < 4; ++ni) {
      const int col = n0 + wn + ni * 16 + l15;
#pragma unroll
      for (int rg = 0; rg < 4; ++rg)
        Pz[(size_t)(row0 + rg) * DH + col] = acc[mi][ni][rg];
    }
  }
}

// Combine: out = cf.x*x + cf.y*c0 + cf.z*c1 + cf.w*(p0+p1+p2+p3)
__global__ __launch_bounds__(256) void moe_combine(const float* __restrict__ P,
                                                   const float* __restrict__ x,
                                                   const float* __restrict__ cc,
                                                   const float* __restrict__ coef,
                                                   float* __restrict__ out) {
  const size_t i = ((size_t)blockIdx.x * 256 + threadIdx.x) * 4;
  const int row = (int)(i >> 11);
  const int col = (int)(i & 2047);
  floatx4 psum = *(const floatx4*)&P[i];
#pragma unroll
  for (int z = 1; z < 4; ++z) {
    const floatx4 pz = *(const floatx4*)&P[(size_t)z * TOKS * DH + i];
#pragma unroll
    for (int e = 0; e < 4; ++e) psum[e] += pz[e];
  }
  const floatx4 xv = *(const floatx4*)&x[i];
  const floatx4 c0 = *(const floatx4*)&cc[col];
  const floatx4 c1 = *(const floatx4*)&cc[DH + col];
  const floatx4 cf = *(const floatx4*)&coef[row * 4];
  floatx4 o;
#pragma unroll
  for (int e = 0; e < 4; ++e)
    o[e] = cf[0] * xv[e] + cf[1] * c0[e] + cf[2] * c1[e] + cf[3] * psum[e];
  *(floatx4*)&out[i] = o;
}

extern "C" void kernel_launch(void* const* d_in, const int* in_sizes, int n_in,
                              void* d_out, int out_size, void* d_ws, size_t ws_size,
                              hipStream_t stream) {
  const float* x   = (const float*)d_in[0];
  const float* gw1 = (const float*)d_in[1];
  const float* gw2 = (const float*)d_in[2];
  const float* cwg = (const float*)d_in[3];
  const float* cc  = (const float*)d_in[4];
  const float* wg  = (const float*)d_in[5];
  const float* wu  = (const float*)d_in[6];
  const float* wd  = (const float*)d_in[7];
  float* out = (float*)d_out;
  float* logits_out = out + (size_t)TOKS * DH;

  // Workspace layout (P aliases xb+wgwuT, which are dead after gemm1):
  //   [0,            16.8 MB)  xb   [4096][2048] bf16      | phase 1
  //   [16.8,        134.2 MB)  wgwuT [16384][2048] bf16    | phase 1
  //   [0,           134.2 MB)  P    [4][4096][2048] fp32   | phase 2
  //   [134.2,       167.8 MB)  wdT  [2048][8192] bf16
  //   [167.8,       234.9 MB)  H    [4096][8192] bf16
  //   [234.9, +64KB)           coef [4096][4] fp32
  char* ws = (char*)d_ws;
  short* xb    = (short*)(ws);
  short* wgwuT = (short*)(ws + 16777216);
  float* P     = (float*)(ws);
  short* wdT   = (short*)(ws + 134217728);
  short* H     = (short*)(ws + 134217728 + 33554432);
  float* coef  = (float*)(ws + 134217728 + 33554432 + 67108864);

  cvt_f32_to_bf16<<<(TOKS * DH) / (256 * 4), 256, 0, stream>>>(x, xb);
  // wg/wu: in [2048][8192] -> interleaved rows of wgwuT (rstride 2)
  transpose_v2<<<dim3(DI / 64, DH / 64), 256, 0, stream>>>(wg, wgwuT, DH, DI, 2, 0);
  transpose_v2<<<dim3(DI / 64, DH / 64), 256, 0, stream>>>(wu, wgwuT, DH, DI, 2, 1);
  // wd: in [8192][2048] -> wdT [2048][8192]
  transpose_v2<<<dim3(DH / 64, DI / 64), 256, 0, stream>>>(wd, wdT, DI, DH, 1, 0);
  router_kernel<<<TOKS / RT_TPB, 256, 0, stream>>>(x, gw1, gw2, cwg, logits_out, coef);
  gemm1_gu_silu<<<dim3((2 * DI) / 128, TOKS / 128), 256, 0, stream>>>(
      xb, wgwuT, H, DH, DH, DH);
  gemm2_splitk<<<dim3(DH / 128, TOKS / 128, 4), 256, 0, stream>>>(
      H, wdT, P, DI / 4, DI, DI);
  moe_combine<<<(TOKS * DH) / (256 * 4), 256, 0, stream>>>(P, x, cc, coef, out);
}